// Round 1
// baseline (326.228 us; speedup 1.0000x reference)
//
#include <hip/hip_runtime.h>

// OnlyMarkovConvolution: out[b,i] = mask[b,i] ? -1e8 : log_softmax_row(w[i]*m[b,i]+b[i])
// B=16384, N=2048. One wave64 per row; 32 elements/lane in registers.

#define BDIM 256
#define NCOLS 2048
#define WAVES_PER_BLOCK 4

__global__ __launch_bounds__(BDIM) void markov_logsoftmax_kernel(
    const float* __restrict__ x_markov,
    const int*   __restrict__ x_mask,
    const float* __restrict__ conv_w,
    const float* __restrict__ conv_b,
    float*       __restrict__ out)
{
    const int wave = threadIdx.x >> 6;
    const int lane = threadIdx.x & 63;
    const long long row = (long long)blockIdx.x * WAVES_PER_BLOCK + wave;

    const float* __restrict__ mrow = x_markov + row * NCOLS;
    const int*   __restrict__ krow = x_mask   + row * NCOLS;
    float*       __restrict__ orow = out      + row * NCOLS;

    // Phase 1: load row, fused affine, running max. 8 float4 chunks per lane.
    float4 t[8];
    float vmax = -3.4e38f;
#pragma unroll
    for (int j = 0; j < 8; ++j) {
        const int idx = (j * 64 + lane) * 4;
        const float4 m = *(const float4*)(mrow + idx);
        const float4 w = *(const float4*)(conv_w + idx);
        const float4 b = *(const float4*)(conv_b + idx);
        float4 v;
        v.x = fmaf(w.x, m.x, b.x);
        v.y = fmaf(w.y, m.y, b.y);
        v.z = fmaf(w.z, m.z, b.z);
        v.w = fmaf(w.w, m.w, b.w);
        t[j] = v;
        vmax = fmaxf(vmax, fmaxf(fmaxf(v.x, v.y), fmaxf(v.z, v.w)));
    }

    // Wave64 max reduction (butterfly).
#pragma unroll
    for (int off = 32; off >= 1; off >>= 1)
        vmax = fmaxf(vmax, __shfl_xor(vmax, off, 64));

    // Phase 2: sum of exp(t - max).
    float sum = 0.f;
#pragma unroll
    for (int j = 0; j < 8; ++j) {
        sum += __expf(t[j].x - vmax);
        sum += __expf(t[j].y - vmax);
        sum += __expf(t[j].z - vmax);
        sum += __expf(t[j].w - vmax);
    }
#pragma unroll
    for (int off = 32; off >= 1; off >>= 1)
        sum += __shfl_xor(sum, off, 64);

    const float c = vmax + __logf(sum);   // t - c = log_softmax

    // Phase 3: mask + store.
#pragma unroll
    for (int j = 0; j < 8; ++j) {
        const int idx = (j * 64 + lane) * 4;
        const int4 msk = *(const int4*)(krow + idx);
        const float4 v = t[j];
        float4 o;
        o.x = msk.x ? -1e8f : (v.x - c);
        o.y = msk.y ? -1e8f : (v.y - c);
        o.z = msk.z ? -1e8f : (v.z - c);
        o.w = msk.w ? -1e8f : (v.w - c);
        *(float4*)(orow + idx) = o;
    }
}

extern "C" void kernel_launch(void* const* d_in, const int* in_sizes, int n_in,
                              void* d_out, int out_size, void* d_ws, size_t ws_size,
                              hipStream_t stream) {
    // setup_inputs order: x(0), x_dist(1), x_features(2), x_markov(3),
    //                     x_week(4), x_mask(5), conv_w(6), conv_b(7)
    const float* x_markov = (const float*)d_in[3];
    const int*   x_mask   = (const int*)d_in[5];
    const float* conv_w   = (const float*)d_in[6];
    const float* conv_b   = (const float*)d_in[7];
    float* out = (float*)d_out;

    const int B = in_sizes[4];               // 16384 (x_week is [B])
    const int grid = B / WAVES_PER_BLOCK;    // 4096 blocks, 4 rows each

    markov_logsoftmax_kernel<<<grid, BDIM, 0, stream>>>(
        x_markov, x_mask, conv_w, conv_b, out);
}